// Round 3
// baseline (236.701 us; speedup 1.0000x reference)
//
#include <hip/hip_runtime.h>

// BlurNet: out[b,0,y,x] = w * bilinear_zero_pad(img[b,0], y+off_y, x+off_x) + bias
// img: [16,1,720,1280] f32, offset: [16,2,720,1280] f32 (ch0=off_y, ch1=off_x)
//
// v3: stride-1 lane mapping for the gather phase (kills the 8-way LDS bank
// conflict of the quad layout); all 16 offset loads issued up-front.

#define NB 16
#define IH 720
#define IW 1280
#define TW 128          // tile width  (10 tiles)
#define TH 16           // tile height (45 tiles)
#define HALO_Y 6        // vertical halo rows each side
#define HX_L 8          // left x halo (keeps staged cols 16B-aligned)
#define SROWS (TH + 2*HALO_Y + 1)   // 29 staged rows: [ty0-6, ty0+22]
#define SCOLS 148                   // staged cols:  [tx0-8, tx0+139]
#define SLOTQ (SCOLS/4)             // 37 float4 slots per row
#define SLOTS (SROWS * SLOTQ)       // 1073

__global__ __launch_bounds__(256) void blurnet_tile(
    const float* __restrict__ img,
    const float* __restrict__ offset,
    const float* __restrict__ weight,
    const float* __restrict__ bias,
    float* __restrict__ out)
{
    __shared__ float ls[SROWS][SCOLS];

    const int HW = IH * IW;
    const int tilesX = IW / TW;              // 10
    const int tilesY = IH / TH;              // 45
    const int nwg = NB * tilesX * tilesY;    // 7200 (% 8 == 0)

    // XCD-aware bijective swizzle
    int bid = blockIdx.x;
    int tile = (bid & 7) * (nwg >> 3) + (bid >> 3);

    int b  = tile / (tilesX * tilesY);
    int tr = tile % (tilesX * tilesY);
    int ty0 = (tr / tilesX) * TH;
    int tx0 = (tr % tilesX) * TW;

    const float* imgb = img + b * HW;

    // ---- stage image window into LDS (coalesced float4, zero-pad OOB) ----
    for (int s = threadIdx.x; s < SLOTS; s += 256) {
        int r  = s / SLOTQ;
        int c4 = s % SLOTQ;
        int gr = ty0 - HALO_Y + r;
        int gc = tx0 - HX_L + c4 * 4;        // multiple of 4 => 16B-aligned
        float4 v;
        if (gr >= 0 && gr < IH && gc >= 0 && gc + 3 < IW) {
            v = *reinterpret_cast<const float4*>(imgb + gr * IW + gc);
        } else {
            float t0 = 0.f, t1 = 0.f, t2 = 0.f, t3 = 0.f;
            if (gr >= 0 && gr < IH) {
                if (gc     >= 0 && gc     < IW) t0 = imgb[gr * IW + gc];
                if (gc + 1 >= 0 && gc + 1 < IW) t1 = imgb[gr * IW + gc + 1];
                if (gc + 2 >= 0 && gc + 2 < IW) t2 = imgb[gr * IW + gc + 2];
                if (gc + 3 >= 0 && gc + 3 < IW) t3 = imgb[gr * IW + gc + 3];
            }
            v = make_float4(t0, t1, t2, t3);
        }
        *reinterpret_cast<float4*>(&ls[r][c4 * 4]) = v;
    }

    // ---- issue all 16 offset loads while staging is in flight ----
    const float* offy = offset + (size_t)b * 2 * HW;
    const float* offx = offy + HW;
    int r0  = threadIdx.x >> 7;              // 0 or 1
    int col = threadIdx.x & 127;
    int gx  = tx0 + col;
    int base0 = (ty0 + r0) * IW + gx;        // rows ty0+r0+2i, i=0..7

    float oys[8], oxs[8];
    #pragma unroll
    for (int i = 0; i < 8; ++i) oys[i] = offy[base0 + i * 2 * IW];
    #pragma unroll
    for (int i = 0; i < 8; ++i) oxs[i] = offx[base0 + i * 2 * IW];

    __syncthreads();

    const float w   = weight[0];
    const float bsv = bias[0];
    const float fgx = (float)gx;

    #pragma unroll
    for (int i = 0; i < 8; ++i) {
        int gy = ty0 + r0 + 2 * i;
        float py = (float)gy + oys[i];
        float px = fgx + oxs[i];
        float fy0 = floorf(py);
        float fx0 = floorf(px);
        int y0 = (int)fy0;
        int x0 = (int)fx0;
        float wy1 = py - fy0, wy0 = 1.0f - wy1;
        float wx1 = px - fx0, wx0 = 1.0f - wx1;

        int lr = y0 - (ty0 - HALO_Y);
        int lc = x0 - (tx0 - HX_L);
        float v00, v01, v10, v11;
        if (lr >= 0 && lr + 1 < SROWS && lc >= 0 && lc + 1 < SCOLS) {
            v00 = ls[lr][lc];
            v01 = ls[lr][lc + 1];
            v10 = ls[lr + 1][lc];
            v11 = ls[lr + 1][lc + 1];
        } else {
            // rare fallback: exact predicated global gathers (zero pad)
            bool yv0 = (y0 >= 0)     && (y0 < IH);
            bool yv1 = (y0 + 1 >= 0) && (y0 + 1 < IH);
            bool xv0 = (x0 >= 0)     && (x0 < IW);
            bool xv1 = (x0 + 1 >= 0) && (x0 + 1 < IW);
            v00 = (yv0 && xv0) ? imgb[y0 * IW + x0]           : 0.0f;
            v01 = (yv0 && xv1) ? imgb[y0 * IW + x0 + 1]       : 0.0f;
            v10 = (yv1 && xv0) ? imgb[(y0 + 1) * IW + x0]     : 0.0f;
            v11 = (yv1 && xv1) ? imgb[(y0 + 1) * IW + x0 + 1] : 0.0f;
        }
        float s = wy0 * (wx0 * v00 + wx1 * v01) + wy1 * (wx0 * v10 + wx1 * v11);
        out[(size_t)b * HW + base0 + i * 2 * IW] = w * s + bsv;
    }
}

extern "C" void kernel_launch(void* const* d_in, const int* in_sizes, int n_in,
                              void* d_out, int out_size, void* d_ws, size_t ws_size,
                              hipStream_t stream) {
    const float* img = (const float*)d_in[0];
    const float* off = (const float*)d_in[1];
    const float* wt  = (const float*)d_in[2];
    const float* bs  = (const float*)d_in[3];
    float* out = (float*)d_out;

    const int blocks = NB * (IH / TH) * (IW / TW);   // 7200
    blurnet_tile<<<blocks, 256, 0, stream>>>(img, off, wt, bs, out);
}

// Round 5
// 235.681 us; speedup vs baseline: 1.0043x; 1.0043x over previous
//
#include <hip/hip_runtime.h>

// BlurNet: out[b,0,y,x] = w * bilinear_zero_pad(img[b,0], y+off_y, x+off_x) + bias
// img: [16,1,720,1280] f32, offset: [16,2,720,1280] f32 (ch0=off_y, ch1=off_x)
//
// v4 (resubmit after infra failure): round-2 quad layout (vectorized I/O) +
// offset prefetch issued BEFORE the barrier + taller tile (TH=24).

#define NB 16
#define IH 720
#define IW 1280
#define TW 128          // tile width  (10 tiles)
#define TH 24           // tile height (30 tiles)
#define HALO_Y 6        // vertical halo rows each side
#define HX_L 8          // left x halo (keeps staged cols 16B-aligned)
#define SROWS (TH + 2*HALO_Y + 1)   // 37 staged rows: [ty0-6, ty0+30]
#define SCOLS 148                   // staged cols:  [tx0-8, tx0+139]
#define SLOTQ (SCOLS/4)             // 37 float4 slots per row
#define SLOTS (SROWS * SLOTQ)       // 1369

__global__ __launch_bounds__(256) void blurnet_tile(
    const float* __restrict__ img,
    const float* __restrict__ offset,
    const float* __restrict__ weight,
    const float* __restrict__ bias,
    float* __restrict__ out)
{
    __shared__ float ls[SROWS][SCOLS];

    const int HW = IH * IW;
    const int tilesX = IW / TW;              // 10
    const int tilesY = IH / TH;              // 30
    const int nwg = NB * tilesX * tilesY;    // 4800 (% 8 == 0)

    // XCD-aware bijective swizzle
    int bid = blockIdx.x;
    int tile = (bid & 7) * (nwg >> 3) + (bid >> 3);

    int b  = tile / (tilesX * tilesY);
    int tr = tile % (tilesX * tilesY);
    int ty0 = (tr / tilesX) * TH;
    int tx0 = (tr % tilesX) * TW;

    const float* imgb = img + b * HW;

    // ---- stage image window into LDS (coalesced float4, zero-pad OOB) ----
    for (int s = threadIdx.x; s < SLOTS; s += 256) {
        int r  = s / SLOTQ;
        int c4 = s % SLOTQ;
        int gr = ty0 - HALO_Y + r;
        int gc = tx0 - HX_L + c4 * 4;        // multiple of 4 => 16B-aligned
        float4 v;
        if (gr >= 0 && gr < IH && gc >= 0 && gc + 3 < IW) {
            v = *reinterpret_cast<const float4*>(imgb + gr * IW + gc);
        } else {
            float t0 = 0.f, t1 = 0.f, t2 = 0.f, t3 = 0.f;
            if (gr >= 0 && gr < IH) {
                if (gc     >= 0 && gc     < IW) t0 = imgb[gr * IW + gc];
                if (gc + 1 >= 0 && gc + 1 < IW) t1 = imgb[gr * IW + gc + 1];
                if (gc + 2 >= 0 && gc + 2 < IW) t2 = imgb[gr * IW + gc + 2];
                if (gc + 3 >= 0 && gc + 3 < IW) t3 = imgb[gr * IW + gc + 3];
            }
            v = make_float4(t0, t1, t2, t3);
        }
        *reinterpret_cast<float4*>(&ls[r][c4 * 4]) = v;
    }

    // ---- prefetch ALL offset quads before the barrier (latency hidden) ----
    const float* offy = offset + (size_t)b * 2 * HW;
    const float* offx = offy + HW;

    float4 oy[3], ox[3];
    int baseq[3];
    #pragma unroll
    for (int j = 0; j < 3; ++j) {
        int q   = threadIdx.x + j * 256;
        int row = q >> 5;                    // 0..23
        int col = (q & 31) << 2;             // 0..124
        int base = (ty0 + row) * IW + tx0 + col;
        baseq[j] = base;
        oy[j] = *reinterpret_cast<const float4*>(offy + base);
        ox[j] = *reinterpret_cast<const float4*>(offx + base);
    }

    __syncthreads();

    const float w   = weight[0];
    const float bsv = bias[0];

    #pragma unroll
    for (int j = 0; j < 3; ++j) {
        int q   = threadIdx.x + j * 256;
        int row = q >> 5;
        int col = (q & 31) << 2;
        int gy  = ty0 + row;
        int gx0 = tx0 + col;

        float oys[4] = {oy[j].x, oy[j].y, oy[j].z, oy[j].w};
        float oxs[4] = {ox[j].x, ox[j].y, ox[j].z, ox[j].w};
        float res[4];

        #pragma unroll
        for (int k = 0; k < 4; ++k) {
            float py = (float)gy + oys[k];
            float px = (float)(gx0 + k) + oxs[k];
            float fy0 = floorf(py);
            float fx0 = floorf(px);
            int y0 = (int)fy0;
            int x0 = (int)fx0;
            float wy1 = py - fy0, wy0 = 1.0f - wy1;
            float wx1 = px - fx0, wx0 = 1.0f - wx1;

            int lr = y0 - (ty0 - HALO_Y);
            int lc = x0 - (tx0 - HX_L);
            float v00, v01, v10, v11;
            if ((unsigned)lr < (unsigned)(SROWS - 1) &&
                (unsigned)lc < (unsigned)(SCOLS - 1)) {
                v00 = ls[lr][lc];
                v01 = ls[lr][lc + 1];
                v10 = ls[lr + 1][lc];
                v11 = ls[lr + 1][lc + 1];
            } else {
                // rare fallback: exact predicated global gathers (zero pad)
                bool yv0 = (y0 >= 0)     && (y0 < IH);
                bool yv1 = (y0 + 1 >= 0) && (y0 + 1 < IH);
                bool xv0 = (x0 >= 0)     && (x0 < IW);
                bool xv1 = (x0 + 1 >= 0) && (x0 + 1 < IW);
                v00 = (yv0 && xv0) ? imgb[y0 * IW + x0]           : 0.0f;
                v01 = (yv0 && xv1) ? imgb[y0 * IW + x0 + 1]       : 0.0f;
                v10 = (yv1 && xv0) ? imgb[(y0 + 1) * IW + x0]     : 0.0f;
                v11 = (yv1 && xv1) ? imgb[(y0 + 1) * IW + x0 + 1] : 0.0f;
            }
            float s = wy0 * (wx0 * v00 + wx1 * v01) + wy1 * (wx0 * v10 + wx1 * v11);
            res[k] = w * s + bsv;
        }
        *reinterpret_cast<float4*>(out + (size_t)b * HW + baseq[j]) =
            make_float4(res[0], res[1], res[2], res[3]);
    }
}

extern "C" void kernel_launch(void* const* d_in, const int* in_sizes, int n_in,
                              void* d_out, int out_size, void* d_ws, size_t ws_size,
                              hipStream_t stream) {
    const float* img = (const float*)d_in[0];
    const float* off = (const float*)d_in[1];
    const float* wt  = (const float*)d_in[2];
    const float* bs  = (const float*)d_in[3];
    float* out = (float*)d_out;

    const int blocks = NB * (IH / TH) * (IW / TW);   // 4800
    blurnet_tile<<<blocks, 256, 0, stream>>>(img, off, wt, bs, out);
}

// Round 7
// 233.108 us; speedup vs baseline: 1.0154x; 1.0110x over previous
//
#include <hip/hip_runtime.h>

// BlurNet: out[b,0,y,x] = w * bilinear_zero_pad(img[b,0], y+off_y, x+off_x) + bias
// img: [16,1,720,1280] f32, offset: [16,2,720,1280] f32 (ch0=off_y, ch1=off_x)
//
// v5 (resubmit after GPU-acquisition timeout): sigma-swizzled LDS layout
// sigma(c) = c + (c>>2).
//   - sigma(4k+j) = 5k+j: staging quads stay contiguous (ds_write_b32 x4)
//   - gather lanes read cols 4k -> sigma = 5k mod 32, bijective over 32 banks
//     (5 odd) => bank conflicts collapse while keeping quad float4 I/O.
// Geometry: TH=16 (r2's proven 8 blocks/CU), HALO_Y=4, exact global fallback.

#define NB 16
#define IH 720
#define IW 1280
#define TW 128          // tile width  (10 tiles)
#define TH 16           // tile height (45 tiles)
#define HALO_Y 4        // vertical halo rows each side
#define HX_L 4          // left x halo
#define SROWS (TH + 2*HALO_Y + 1)   // 25 staged rows: [ty0-4, ty0+20]
#define SCOLS 140                   // staged cols:  [tx0-4, tx0+135]
#define LSTRIDE 176                 // sigma(139)=173 -> pad to 176 floats/row
#define SLOTQ (SCOLS/4)             // 35 float4 slots per row
#define SLOTS (SROWS * SLOTQ)       // 875

__global__ __launch_bounds__(256) void blurnet_tile(
    const float* __restrict__ img,
    const float* __restrict__ offset,
    const float* __restrict__ weight,
    const float* __restrict__ bias,
    float* __restrict__ out)
{
    __shared__ float ls[SROWS * LSTRIDE];   // 17.6 KB

    const int HW = IH * IW;
    const int tilesX = IW / TW;              // 10
    const int tilesY = IH / TH;              // 45
    const int nwg = NB * tilesX * tilesY;    // 7200 (% 8 == 0)

    // XCD-aware bijective swizzle
    int bid = blockIdx.x;
    int tile = (bid & 7) * (nwg >> 3) + (bid >> 3);

    int b  = tile / (tilesX * tilesY);
    int tr = tile % (tilesX * tilesY);
    int ty0 = (tr / tilesX) * TH;
    int tx0 = (tr % tilesX) * TW;

    const float* imgb = img + b * HW;

    // ---- stage image window into LDS (float4 global loads, sigma layout) ----
    for (int s = threadIdx.x; s < SLOTS; s += 256) {
        int r  = s / SLOTQ;
        int c4 = s - r * SLOTQ;
        int gr = ty0 - HALO_Y + r;
        int gc = tx0 - HX_L + c4 * 4;        // multiple of 4 => 16B-aligned
        float4 v;
        if (gr >= 0 && gr < IH && gc >= 0 && gc + 3 < IW) {
            v = *reinterpret_cast<const float4*>(imgb + gr * IW + gc);
        } else {
            float t0 = 0.f, t1 = 0.f, t2 = 0.f, t3 = 0.f;
            if (gr >= 0 && gr < IH) {
                if (gc     >= 0 && gc     < IW) t0 = imgb[gr * IW + gc];
                if (gc + 1 >= 0 && gc + 1 < IW) t1 = imgb[gr * IW + gc + 1];
                if (gc + 2 >= 0 && gc + 2 < IW) t2 = imgb[gr * IW + gc + 2];
                if (gc + 3 >= 0 && gc + 3 < IW) t3 = imgb[gr * IW + gc + 3];
            }
            v = make_float4(t0, t1, t2, t3);
        }
        int base = r * LSTRIDE + 5 * c4;     // sigma(4*c4) = 5*c4
        ls[base + 0] = v.x;
        ls[base + 1] = v.y;
        ls[base + 2] = v.z;
        ls[base + 3] = v.w;
    }

    // ---- offset quad prefetch (cheap; values live in regs after barrier) ----
    const float* offy = offset + (size_t)b * 2 * HW;
    const float* offx = offy + HW;
    float4 oy[2], ox[2];
    int baseq[2];
    #pragma unroll
    for (int j = 0; j < 2; ++j) {
        int q   = threadIdx.x + j * 256;
        int row = q >> 5;                    // 0..15
        int col = (q & 31) << 2;             // 0..124
        int base = (ty0 + row) * IW + tx0 + col;
        baseq[j] = base;
        oy[j] = *reinterpret_cast<const float4*>(offy + base);
        ox[j] = *reinterpret_cast<const float4*>(offx + base);
    }

    __syncthreads();

    const float w   = weight[0];
    const float bsv = bias[0];

    #pragma unroll
    for (int j = 0; j < 2; ++j) {
        int q   = threadIdx.x + j * 256;
        int row = q >> 5;
        int col = (q & 31) << 2;
        int gy  = ty0 + row;
        int gx0 = tx0 + col;

        float oys[4] = {oy[j].x, oy[j].y, oy[j].z, oy[j].w};
        float oxs[4] = {ox[j].x, ox[j].y, ox[j].z, ox[j].w};
        float res[4];

        #pragma unroll
        for (int k = 0; k < 4; ++k) {
            float py = (float)gy + oys[k];
            float px = (float)(gx0 + k) + oxs[k];
            float fy0 = floorf(py);
            float fx0 = floorf(px);
            int y0 = (int)fy0;
            int x0 = (int)fx0;
            float wy1 = py - fy0, wy0 = 1.0f - wy1;
            float wx1 = px - fx0, wx0 = 1.0f - wx1;

            int lr = y0 - (ty0 - HALO_Y);
            int lc = x0 - (tx0 - HX_L);
            float v00, v01, v10, v11;
            if ((unsigned)lr < (unsigned)(SROWS - 1) &&
                (unsigned)lc < (unsigned)(SCOLS - 1)) {
                int lc1 = lc + 1;
                int a0 = lr * LSTRIDE + lc  + (lc  >> 2);   // sigma(lc)
                int a1 = lr * LSTRIDE + lc1 + (lc1 >> 2);   // sigma(lc+1)
                v00 = ls[a0];
                v10 = ls[a0 + LSTRIDE];
                v01 = ls[a1];
                v11 = ls[a1 + LSTRIDE];
            } else {
                // rare fallback: exact predicated global gathers (zero pad)
                bool yv0 = (y0 >= 0)     && (y0 < IH);
                bool yv1 = (y0 + 1 >= 0) && (y0 + 1 < IH);
                bool xv0 = (x0 >= 0)     && (x0 < IW);
                bool xv1 = (x0 + 1 >= 0) && (x0 + 1 < IW);
                v00 = (yv0 && xv0) ? imgb[y0 * IW + x0]           : 0.0f;
                v01 = (yv0 && xv1) ? imgb[y0 * IW + x0 + 1]       : 0.0f;
                v10 = (yv1 && xv0) ? imgb[(y0 + 1) * IW + x0]     : 0.0f;
                v11 = (yv1 && xv1) ? imgb[(y0 + 1) * IW + x0 + 1] : 0.0f;
            }
            float s = wy0 * (wx0 * v00 + wx1 * v01) + wy1 * (wx0 * v10 + wx1 * v11);
            res[k] = w * s + bsv;
        }
        *reinterpret_cast<float4*>(out + (size_t)b * HW + baseq[j]) =
            make_float4(res[0], res[1], res[2], res[3]);
    }
}

extern "C" void kernel_launch(void* const* d_in, const int* in_sizes, int n_in,
                              void* d_out, int out_size, void* d_ws, size_t ws_size,
                              hipStream_t stream) {
    const float* img = (const float*)d_in[0];
    const float* off = (const float*)d_in[1];
    const float* wt  = (const float*)d_in[2];
    const float* bs  = (const float*)d_in[3];
    float* out = (float*)d_out;

    const int blocks = NB * (IH / TH) * (IW / TW);   // 7200
    blurnet_tile<<<blocks, 256, 0, stream>>>(img, off, wt, bs, out);
}